// Round 5
// baseline (2064.726 us; speedup 1.0000x reference)
//
#include <hip/hip_runtime.h>
#include <hip/hip_bf16.h>
#include <cstdint>

#define NN 100000
#define NE 1600000
#define HID 64
#define EPS 1e-5f

typedef __bf16 bf16_t;
typedef __attribute__((ext_vector_type(8))) __bf16 bf16x8;
typedef __attribute__((ext_vector_type(4))) float f32x4;

#define LDS_FENCE() asm volatile("s_waitcnt lgkmcnt(0)" ::: "memory")

// ---------------- dtype detectors ----------------
// flags[0]: 1 iff float inputs are bf16 (else f32). flags[1]: 1 iff edge_index is int64.
__global__ void k_detect(const unsigned* __restrict__ xw, const int* __restrict__ eiw,
                         int* __restrict__ flags) {
  int lane = threadIdx.x;  // 64
  unsigned u = xw[lane];
  unsigned lo = u & 0xFFFFu;
  unsigned e = (lo >> 7) & 0xFFu;
  bool bf_ok = (lo == 0u) || (e >= 0x50u && e <= 0x8Fu);
  unsigned long long b1 = __ballot(bf_ok);
  int v = eiw[2 * lane + 1];
  unsigned long long b2 = __ballot(v == 0);
  if (lane == 0) {
    flags[0] = (b1 == ~0ull) ? 1 : 0;
    flags[1] = (b2 == ~0ull) ? 1 : 0;
  }
}

// ---------------- input canonicalization ----------------
struct FPtrs {
  const void* p[17];
  int len[17];
  int ofs[17];
};

template <typename FT>
__global__ void k_cvt_f(FPtrs fp, float* __restrict__ canon, const int* __restrict__ flags,
                        int total) {
  if (flags[0] != (int)(sizeof(FT) == 2)) return;
  int i = blockIdx.x * blockDim.x + threadIdx.x;
  int stride = gridDim.x * blockDim.x;
  for (int t = i; t < total; t += stride) {
    int seg = 0;
    while (seg < 16 && t >= fp.ofs[seg] + fp.len[seg]) ++seg;
    canon[t] = (float)((const FT*)fp.p[seg])[t - fp.ofs[seg]];
  }
}

template <typename IT>
__global__ void k_cvt_idx(const IT* __restrict__ ei, int* __restrict__ eic,
                          const int* __restrict__ flags) {
  if (flags[1] != (int)(sizeof(IT) == 8)) return;
  int i = blockIdx.x * blockDim.x + threadIdx.x;
  int stride = gridDim.x * blockDim.x;
  for (int t = i; t < 2 * NE; t += stride) eic[t] = (int)ei[t];
}

// ---------------- utility: zero fill ----------------
__global__ void k_zero4(f32x4* __restrict__ p, int n4) {
  int i = blockIdx.x * blockDim.x + threadIdx.x;
  int stride = gridDim.x * blockDim.x;
  f32x4 z = {0.f, 0.f, 0.f, 0.f};
  for (int t = i; t < n4; t += stride) p[t] = z;
}

// ---------------- degree / dinv ----------------
__global__ void k_deg(const int* __restrict__ eic, float* __restrict__ deg) {
  int i = blockIdx.x * blockDim.x + threadIdx.x;
  int stride = gridDim.x * blockDim.x;
  for (int e = i; e < NE; e += stride) unsafeAtomicAdd(&deg[eic[NE + e]], 1.0f);
}

__global__ void k_dinv(float* __restrict__ d) {
  int n = blockIdx.x * blockDim.x + threadIdx.x;
  if (n < NN) d[n] = rsqrtf(d[n] + 1.0f);
}

// ---------------- layer 1: hs = (x @ W1) * dinv ----------------
__global__ void k_xw1(const float* __restrict__ x, const float* __restrict__ W1,
                      const float* __restrict__ dinv, float* __restrict__ hs) {
  int gid = blockIdx.x * blockDim.x + threadIdx.x;
  if (gid >= NN * HID) return;
  int n = gid >> 6, j = gid & 63;
  float acc = x[n * 3 + 0] * W1[0 * 64 + j] + x[n * 3 + 1] * W1[1 * 64 + j] +
              x[n * 3 + 2] * W1[2 * 64 + j];
  hs[gid] = acc * dinv[n];
}

// ---------------- hs = (h @ W) * dinv ----------------
__global__ __launch_bounds__(256) void k_hw(const float* __restrict__ h,
                                            const float* __restrict__ W,
                                            const float* __restrict__ dinv,
                                            float* __restrict__ hs) {
  __shared__ float Wl[64 * 64];
  __shared__ float hrow[4][64];
  int tid = threadIdx.x;
  for (int i = tid; i < 64 * 64; i += 256) Wl[i] = W[i];
  __syncthreads();
  int w = tid >> 6, j = tid & 63;
  for (int nb = blockIdx.x * 4 + w; nb < NN; nb += gridDim.x * 4) {
    hrow[w][j] = h[nb * 64 + j];
    LDS_FENCE();
    float acc = 0.f;
#pragma unroll 8
    for (int k = 0; k < 64; ++k) acc += hrow[w][k] * Wl[k * 64 + j];
    hs[nb * 64 + j] = acc * dinv[nb];
  }
}

// ---------------- scatter: agg[col] += hs[row] ----------------
__global__ void k_scatter(const int* __restrict__ eic, const float* __restrict__ hs,
                          float* __restrict__ agg) {
  int i = blockIdx.x * blockDim.x + threadIdx.x;
  int stride = gridDim.x * blockDim.x;
  const int total = NE * 64;
  for (int t = i; t < total; t += stride) {
    int e = t >> 6, j = t & 63;
    unsafeAtomicAdd(&agg[eic[NE + e] * 64 + j], hs[eic[e] * 64 + j]);
  }
}

// ---------------- finalize layers 1-2: agg = relu(dinv*(agg+hs)+b) in place ----------------
__global__ void k_finalize_relu(float* __restrict__ agg, const float* __restrict__ hs,
                                const float* __restrict__ dinv, const float* __restrict__ b) {
  int gid = blockIdx.x * blockDim.x + threadIdx.x;
  if (gid >= NN * HID) return;
  int n = gid >> 6, j = gid & 63;
  agg[gid] = fmaxf((agg[gid] + hs[gid]) * dinv[n] + b[j], 0.f);
}

// ---------------- finalize layer 3: h3 -> bf16 hi/lo split rows of 128 ----------------
__global__ void k_h3split(const float* __restrict__ agg, const float* __restrict__ hs,
                          const float* __restrict__ dinv, const float* __restrict__ b,
                          bf16_t* __restrict__ h3p) {
  int gid = blockIdx.x * blockDim.x + threadIdx.x;
  if (gid >= NN * HID) return;
  int n = gid >> 6, j = gid & 63;
  float v = (agg[gid] + hs[gid]) * dinv[n] + b[j];
  bf16_t hi = (bf16_t)v;
  bf16_t lo = (bf16_t)(v - (float)hi);
  h3p[n * 128 + j] = hi;
  h3p[n * 128 + 64 + j] = lo;
}

// ---------------- shared MLP helpers ----------------
// a1 tile in C-layout: a1c[ct][r] = relu(ef @ Wm1 + bm1) at row q*4+r, col ct*16+n.
// A-split (h3 hi+lo), B exact bf16.
__device__ __forceinline__ void compute_a1(const int* __restrict__ eic,
                                           const bf16_t* __restrict__ h3p, int t, int n, int q,
                                           const bf16x8 b1h[4][4], const float bias1[4],
                                           f32x4 a1c[4]) {
  int e = t * 16 + n;
  int src = eic[e], dst = eic[NE + e];
  const bf16x8* ps = (const bf16x8*)(h3p + src * 128);
  const bf16x8* pd = (const bf16x8*)(h3p + dst * 128);
  bf16x8 a0h = ps[q], a1h = ps[4 + q], a0l = ps[8 + q], a1l = ps[12 + q];
  bf16x8 a2h = pd[q], a3h = pd[4 + q], a2l = pd[8 + q], a3l = pd[12 + q];
#pragma unroll
  for (int ct = 0; ct < 4; ++ct) {
    f32x4 c = {0.f, 0.f, 0.f, 0.f};
    c = __builtin_amdgcn_mfma_f32_16x16x32_bf16(a0h, b1h[0][ct], c, 0, 0, 0);
    c = __builtin_amdgcn_mfma_f32_16x16x32_bf16(a0l, b1h[0][ct], c, 0, 0, 0);
    c = __builtin_amdgcn_mfma_f32_16x16x32_bf16(a1h, b1h[1][ct], c, 0, 0, 0);
    c = __builtin_amdgcn_mfma_f32_16x16x32_bf16(a1l, b1h[1][ct], c, 0, 0, 0);
    c = __builtin_amdgcn_mfma_f32_16x16x32_bf16(a2h, b1h[2][ct], c, 0, 0, 0);
    c = __builtin_amdgcn_mfma_f32_16x16x32_bf16(a2l, b1h[2][ct], c, 0, 0, 0);
    c = __builtin_amdgcn_mfma_f32_16x16x32_bf16(a3h, b1h[3][ct], c, 0, 0, 0);
    c = __builtin_amdgcn_mfma_f32_16x16x32_bf16(a3l, b1h[3][ct], c, 0, 0, 0);
#pragma unroll
    for (int r = 0; r < 4; ++r) a1c[ct][r] = fmaxf(c[r] + bias1[ct], 0.f);
  }
}

__device__ __forceinline__ void load_b1(const float* __restrict__ Wm1f, int n, int q,
                                        bf16x8 b1h[4][4], const float* __restrict__ bm1f,
                                        float bias1[4]) {
#pragma unroll
  for (int ks = 0; ks < 4; ++ks)
#pragma unroll
    for (int ct = 0; ct < 4; ++ct)
#pragma unroll
      for (int j = 0; j < 8; ++j)
        b1h[ks][ct][j] = (bf16_t)Wm1f[(ks * 32 + q * 8 + j) * 64 + ct * 16 + n];
#pragma unroll
  for (int ct = 0; ct < 4; ++ct) bias1[ct] = bm1f[ct * 16 + n];
}

// z1 (f32, C-layout) -> LDS -> A-layout f32 -> hi/lo split -> a2 = relu(z1 @ Wm2 + bm2)
__device__ __forceinline__ void compute_a2(float zt[16][68], int wv_unused, int n, int q,
                                           const f32x4 a1c[4], const float s1c[4],
                                           const float t1c[4], const bf16x8 b2h[2][2],
                                           const float bias2[2], f32x4 a2c[2]) {
#pragma unroll
  for (int ct = 0; ct < 4; ++ct)
#pragma unroll
    for (int r = 0; r < 4; ++r)
      zt[q * 4 + r][ct * 16 + n] = a1c[ct][r] * s1c[ct] + t1c[ct];
  LDS_FENCE();
  bf16x8 g0h, g0l, g1h, g1l;
#pragma unroll
  for (int j = 0; j < 8; ++j) {
    float z0 = zt[n][q * 8 + j];
    float z1 = zt[n][32 + q * 8 + j];
    bf16_t h0 = (bf16_t)z0, h1 = (bf16_t)z1;
    g0h[j] = h0; g0l[j] = (bf16_t)(z0 - (float)h0);
    g1h[j] = h1; g1l[j] = (bf16_t)(z1 - (float)h1);
  }
#pragma unroll
  for (int ct = 0; ct < 2; ++ct) {
    f32x4 c = {0.f, 0.f, 0.f, 0.f};
    c = __builtin_amdgcn_mfma_f32_16x16x32_bf16(g0h, b2h[0][ct], c, 0, 0, 0);
    c = __builtin_amdgcn_mfma_f32_16x16x32_bf16(g0l, b2h[0][ct], c, 0, 0, 0);
    c = __builtin_amdgcn_mfma_f32_16x16x32_bf16(g1h, b2h[1][ct], c, 0, 0, 0);
    c = __builtin_amdgcn_mfma_f32_16x16x32_bf16(g1l, b2h[1][ct], c, 0, 0, 0);
#pragma unroll
    for (int r = 0; r < 4; ++r) a2c[ct][r] = fmaxf(c[r] + bias2[ct], 0.f);
  }
}

__device__ __forceinline__ void load_b2(const float* __restrict__ Wm2f, int n, int q,
                                        bf16x8 b2h[2][2], const float* __restrict__ bm2f,
                                        float bias2[2]) {
#pragma unroll
  for (int ks = 0; ks < 2; ++ks)
#pragma unroll
    for (int ct = 0; ct < 2; ++ct)
#pragma unroll
      for (int j = 0; j < 8; ++j)
        b2h[ks][ct][j] = (bf16_t)Wm2f[(ks * 32 + q * 8 + j) * 32 + ct * 16 + n];
#pragma unroll
  for (int ct = 0; ct < 2; ++ct) bias2[ct] = bm2f[ct * 16 + n];
}

// ============ pass 1: stats of a1 ============
__global__ __launch_bounds__(256) void k_stats1(const int* __restrict__ eic,
                                                const bf16_t* __restrict__ h3p,
                                                const float* __restrict__ Wm1f,
                                                const float* __restrict__ bm1f,
                                                float* __restrict__ sum1,
                                                float* __restrict__ sq1) {
  int lane = threadIdx.x & 63;
  int wave = blockIdx.x * 4 + (threadIdx.x >> 6);
  int nwaves = gridDim.x * 4;
  int n = lane & 15, q = lane >> 4;
  bf16x8 b1h[4][4];
  float bias1[4];
  load_b1(Wm1f, n, q, b1h, bm1f, bias1);
  float accs[4] = {0, 0, 0, 0}, accq[4] = {0, 0, 0, 0};
  for (int t = wave; t < NE / 16; t += nwaves) {
    f32x4 a1c[4];
    compute_a1(eic, h3p, t, n, q, b1h, bias1, a1c);
#pragma unroll
    for (int ct = 0; ct < 4; ++ct)
#pragma unroll
      for (int r = 0; r < 4; ++r) {
        accs[ct] += a1c[ct][r];
        accq[ct] += a1c[ct][r] * a1c[ct][r];
      }
  }
#pragma unroll
  for (int ct = 0; ct < 4; ++ct) {
    float s = accs[ct], qq = accq[ct];
    s += __shfl_xor(s, 16); s += __shfl_xor(s, 32);
    qq += __shfl_xor(qq, 16); qq += __shfl_xor(qq, 32);
    if (lane < 16) {
      unsafeAtomicAdd(&sum1[ct * 16 + lane], s);
      unsafeAtomicAdd(&sq1[ct * 16 + lane], qq);
    }
  }
}

// ---------------- BN affine constants: s = g*rsqrt(var+eps), t = be - mu*s ----------------
__global__ void k_bnconst(const float* __restrict__ sum, const float* __restrict__ sq,
                          const float* __restrict__ g, const float* __restrict__ be,
                          float* __restrict__ sarr, float* __restrict__ tarr, int ncol) {
  int j = threadIdx.x;
  if (j >= ncol) return;
  float mu = sum[j] / (float)NE;
  float var = fmaxf(sq[j] / (float)NE - mu * mu, 0.f);
  float s = g[j] * rsqrtf(var + EPS);
  sarr[j] = s;
  tarr[j] = be[j] - mu * s;
}

// ============ pass 2: stats of a2 ============
__global__ __launch_bounds__(256) void k_stats2(const int* __restrict__ eic,
                                                const bf16_t* __restrict__ h3p,
                                                const float* __restrict__ Wm1f,
                                                const float* __restrict__ bm1f,
                                                const float* __restrict__ s1, const float* __restrict__ t1,
                                                const float* __restrict__ Wm2f,
                                                const float* __restrict__ bm2f,
                                                float* __restrict__ sum2,
                                                float* __restrict__ sq2) {
  __shared__ float zt[4][16][68];
  int lane = threadIdx.x & 63;
  int wv = threadIdx.x >> 6;
  int wave = blockIdx.x * 4 + wv;
  int nwaves = gridDim.x * 4;
  int n = lane & 15, q = lane >> 4;
  bf16x8 b1h[4][4];
  float bias1[4];
  load_b1(Wm1f, n, q, b1h, bm1f, bias1);
  bf16x8 b2h[2][2];
  float bias2[2];
  load_b2(Wm2f, n, q, b2h, bm2f, bias2);
  float s1c[4], t1c[4];
#pragma unroll
  for (int ct = 0; ct < 4; ++ct) { s1c[ct] = s1[ct * 16 + n]; t1c[ct] = t1[ct * 16 + n]; }
  float accs[2] = {0, 0}, accq[2] = {0, 0};
  for (int t = wave; t < NE / 16; t += nwaves) {
    f32x4 a1c[4], a2c[2];
    compute_a1(eic, h3p, t, n, q, b1h, bias1, a1c);
    compute_a2(zt[wv], wv, n, q, a1c, s1c, t1c, b2h, bias2, a2c);
#pragma unroll
    for (int ct = 0; ct < 2; ++ct)
#pragma unroll
      for (int r = 0; r < 4; ++r) {
        accs[ct] += a2c[ct][r];
        accq[ct] += a2c[ct][r] * a2c[ct][r];
      }
  }
#pragma unroll
  for (int ct = 0; ct < 2; ++ct) {
    float s = accs[ct], qq = accq[ct];
    s += __shfl_xor(s, 16); s += __shfl_xor(s, 32);
    qq += __shfl_xor(qq, 16); qq += __shfl_xor(qq, 32);
    if (lane < 16) {
      unsafeAtomicAdd(&sum2[ct * 16 + lane], s);
      unsafeAtomicAdd(&sq2[ct * 16 + lane], qq);
    }
  }
}

// ============ pass 3: full recompute + BN2 + final dot -> out ============
template <typename OT>
__global__ __launch_bounds__(256) void k_out(const int* __restrict__ eic,
                                             const bf16_t* __restrict__ h3p,
                                             const float* __restrict__ Wm1f,
                                             const float* __restrict__ bm1f,
                                             const float* __restrict__ s1, const float* __restrict__ t1,
                                             const float* __restrict__ Wm2f,
                                             const float* __restrict__ bm2f,
                                             const float* __restrict__ s2, const float* __restrict__ t2,
                                             const float* __restrict__ Wm3f,
                                             const float* __restrict__ bm3f,
                                             OT* __restrict__ out,
                                             const int* __restrict__ flags) {
  if (flags[0] != (int)(sizeof(OT) == 2)) return;
  __shared__ float zt[4][16][68];
  int lane = threadIdx.x & 63;
  int wv = threadIdx.x >> 6;
  int wave = blockIdx.x * 4 + wv;
  int nwaves = gridDim.x * 4;
  int n = lane & 15, q = lane >> 4;
  bf16x8 b1h[4][4];
  float bias1[4];
  load_b1(Wm1f, n, q, b1h, bm1f, bias1);
  bf16x8 b2h[2][2];
  float bias2[2];
  load_b2(Wm2f, n, q, b2h, bm2f, bias2);
  float s1c[4], t1c[4];
#pragma unroll
  for (int ct = 0; ct < 4; ++ct) { s1c[ct] = s1[ct * 16 + n]; t1c[ct] = t1[ct * 16 + n]; }
  float s2c[2], t2c[2];
#pragma unroll
  for (int ct = 0; ct < 2; ++ct) { s2c[ct] = s2[ct * 16 + n]; t2c[ct] = t2[ct * 16 + n]; }
  // per-lane W3 coefficients for columns {n, 16+n}
  float w3a0 = Wm3f[n * 2 + 0], w3a1 = Wm3f[n * 2 + 1];
  float w3b0 = Wm3f[(16 + n) * 2 + 0], w3b1 = Wm3f[(16 + n) * 2 + 1];
  float bb0 = bm3f[0], bb1 = bm3f[1];

  for (int t = wave; t < NE / 16; t += nwaves) {
    f32x4 a1c[4], a2c[2];
    compute_a1(eic, h3p, t, n, q, b1h, bias1, a1c);
    compute_a2(zt[wv], wv, n, q, a1c, s1c, t1c, b2h, bias2, a2c);
#pragma unroll
    for (int r = 0; r < 4; ++r) {
      float z0 = a2c[0][r] * s2c[0] + t2c[0];  // col n
      float z1 = a2c[1][r] * s2c[1] + t2c[1];  // col 16+n
      float o0 = z0 * w3a0 + z1 * w3b0;
      float o1 = z0 * w3a1 + z1 * w3b1;
      o0 += __shfl_xor(o0, 1); o0 += __shfl_xor(o0, 2);
      o0 += __shfl_xor(o0, 4); o0 += __shfl_xor(o0, 8);
      o1 += __shfl_xor(o1, 1); o1 += __shfl_xor(o1, 2);
      o1 += __shfl_xor(o1, 4); o1 += __shfl_xor(o1, 8);
      if (n == 0) {
        int eo = t * 16 + q * 4 + r;
        out[eo * 2 + 0] = (OT)(o0 + bb0);
        out[eo * 2 + 1] = (OT)(o1 + bb1);
      }
    }
  }
}

// ---------------- host ----------------
extern "C" void kernel_launch(void* const* d_in, const int* in_sizes, int n_in,
                              void* d_out, int out_size, void* d_ws, size_t ws_size,
                              hipStream_t stream) {
  (void)n_in; (void)in_sizes; (void)out_size; (void)ws_size;

  char* ws = (char*)d_ws;
  size_t off = 0;
  auto alloc = [&](size_t bytes) {
    size_t r = off;
    off = (off + bytes + 255) & ~(size_t)255;
    return r;
  };
  float* dinv  = (float*)(ws + alloc((size_t)NN * 4));
  float* hs    = (float*)(ws + alloc((size_t)NN * HID * 4));
  float* agg   = (float*)(ws + alloc((size_t)NN * HID * 4));
  bf16_t* h3p  = (bf16_t*)(ws + alloc((size_t)NN * 128 * 2));  // hi/lo rows of 128
  int*   eic   = (int*)(ws + alloc((size_t)2 * NE * 4));
  float* stats = (float*)(ws + alloc(192 * 4));
  float* sum1 = stats, *sq1 = stats + 64, *sum2 = stats + 128, *sq2 = stats + 160;
  int*   flags = (int*)(ws + alloc(256));
  float* s1arr = (float*)(ws + alloc(64 * 4));
  float* t1arr = (float*)(ws + alloc(64 * 4));
  float* s2arr = (float*)(ws + alloc(32 * 4));
  float* t2arr = (float*)(ws + alloc(32 * 4));

  // canonical f32 input block
  static const int flens[17] = {NN * 3, 3 * 64, 64, 64 * 64, 64, 64 * 64, 64,
                                128 * 64, 64, 64, 64, 64 * 32, 32, 32, 32, 32 * 2, 2};
  FPtrs fp;
  int total_f = 0;
  {
    int fi = 0;
    for (int i = 0; i < 18; ++i) {
      if (i == 1) continue;
      fp.p[fi] = d_in[i];
      fp.len[fi] = flens[fi];
      fp.ofs[fi] = total_f;
      total_f += flens[fi];
      ++fi;
    }
  }
  float* canon = (float*)(ws + alloc((size_t)total_f * 4));

  const float* xf   = canon + fp.ofs[0];
  const float* W1f  = canon + fp.ofs[1];
  const float* b1f  = canon + fp.ofs[2];
  const float* W2f  = canon + fp.ofs[3];
  const float* b2f  = canon + fp.ofs[4];
  const float* W3f  = canon + fp.ofs[5];
  const float* b3f  = canon + fp.ofs[6];
  const float* Wm1f = canon + fp.ofs[7];
  const float* bm1f = canon + fp.ofs[8];
  const float* g1f  = canon + fp.ofs[9];
  const float* be1f = canon + fp.ofs[10];
  const float* Wm2f = canon + fp.ofs[11];
  const float* bm2f = canon + fp.ofs[12];
  const float* g2f  = canon + fp.ofs[13];
  const float* be2f = canon + fp.ofs[14];
  const float* Wm3f = canon + fp.ofs[15];
  const float* bm3f = canon + fp.ofs[16];

  const int nh = NN * HID;

  // 0) detect dtypes, canonicalize
  k_detect<<<1, 64, 0, stream>>>((const unsigned*)d_in[0], (const int*)d_in[1], flags);
  k_cvt_idx<int><<<1600, 256, 0, stream>>>((const int*)d_in[1], eic, flags);
  k_cvt_idx<long long><<<1600, 256, 0, stream>>>((const long long*)d_in[1], eic, flags);
  k_cvt_f<float><<<640, 256, 0, stream>>>(fp, canon, flags, total_f);
  k_cvt_f<bf16_t><<<640, 256, 0, stream>>>(fp, canon, flags, total_f);

  // 1) degree / dinv
  k_zero4<<<128, 256, 0, stream>>>((f32x4*)dinv, NN / 4);
  k_zero4<<<1, 64, 0, stream>>>((f32x4*)stats, 48);
  k_deg<<<1024, 256, 0, stream>>>(eic, dinv);
  k_dinv<<<(NN + 255) / 256, 256, 0, stream>>>(dinv);

  // ---- GCN layer 1 ----
  k_xw1<<<(nh + 255) / 256, 256, 0, stream>>>(xf, W1f, dinv, hs);
  k_zero4<<<1600, 256, 0, stream>>>((f32x4*)agg, nh / 4);
  k_scatter<<<25600, 256, 0, stream>>>(eic, hs, agg);
  k_finalize_relu<<<(nh + 255) / 256, 256, 0, stream>>>(agg, hs, dinv, b1f);

  // ---- GCN layer 2 ----
  k_hw<<<4096, 256, 0, stream>>>(agg, W2f, dinv, hs);
  k_zero4<<<1600, 256, 0, stream>>>((f32x4*)agg, nh / 4);
  k_scatter<<<25600, 256, 0, stream>>>(eic, hs, agg);
  k_finalize_relu<<<(nh + 255) / 256, 256, 0, stream>>>(agg, hs, dinv, b2f);

  // ---- GCN layer 3 (no relu; bf16 hi/lo split) ----
  k_hw<<<4096, 256, 0, stream>>>(agg, W3f, dinv, hs);
  k_zero4<<<1600, 256, 0, stream>>>((f32x4*)agg, nh / 4);
  k_scatter<<<25600, 256, 0, stream>>>(eic, hs, agg);
  k_h3split<<<(nh + 255) / 256, 256, 0, stream>>>(agg, hs, dinv, b3f, h3p);

  // ---- edge MLP (3-pass, BN applied in-register post-stats) ----
  k_stats1<<<2048, 256, 0, stream>>>(eic, h3p, Wm1f, bm1f, sum1, sq1);
  k_bnconst<<<1, 64, 0, stream>>>(sum1, sq1, g1f, be1f, s1arr, t1arr, 64);
  k_stats2<<<2048, 256, 0, stream>>>(eic, h3p, Wm1f, bm1f, s1arr, t1arr, Wm2f, bm2f, sum2, sq2);
  k_bnconst<<<1, 64, 0, stream>>>(sum2, sq2, g2f, be2f, s2arr, t2arr, 32);
  k_out<float><<<2048, 256, 0, stream>>>(eic, h3p, Wm1f, bm1f, s1arr, t1arr, Wm2f, bm2f,
                                         s2arr, t2arr, Wm3f, bm3f, (float*)d_out, flags);
  k_out<bf16_t><<<2048, 256, 0, stream>>>(eic, h3p, Wm1f, bm1f, s1arr, t1arr, Wm2f, bm2f,
                                          s2arr, t2arr, Wm3f, bm3f, (bf16_t*)d_out, flags);
}

// Round 6
// 1331.200 us; speedup vs baseline: 1.5510x; 1.5510x over previous
//
#include <hip/hip_runtime.h>
#include <hip/hip_bf16.h>
#include <cstdint>

#define NN 100000
#define NE 1600000
#define HID 64
#define EPS 1e-5f

typedef __bf16 bf16_t;
typedef __attribute__((ext_vector_type(8))) __bf16 bf16x8;
typedef __attribute__((ext_vector_type(4))) float f32x4;

#define LDS_FENCE() asm volatile("s_waitcnt lgkmcnt(0)" ::: "memory")

// ---------------- dtype detectors ----------------
__global__ void k_detect(const unsigned* __restrict__ xw, const int* __restrict__ eiw,
                         int* __restrict__ flags) {
  int lane = threadIdx.x;  // 64
  unsigned u = xw[lane];
  unsigned lo = u & 0xFFFFu;
  unsigned e = (lo >> 7) & 0xFFu;
  bool bf_ok = (lo == 0u) || (e >= 0x50u && e <= 0x8Fu);
  unsigned long long b1 = __ballot(bf_ok);
  int v = eiw[2 * lane + 1];
  unsigned long long b2 = __ballot(v == 0);
  if (lane == 0) {
    flags[0] = (b1 == ~0ull) ? 1 : 0;
    flags[1] = (b2 == ~0ull) ? 1 : 0;
  }
}

// ---------------- input canonicalization ----------------
struct FPtrs {
  const void* p[17];
  int len[17];
  int ofs[17];
};

template <typename FT>
__global__ void k_cvt_f(FPtrs fp, float* __restrict__ canon, const int* __restrict__ flags,
                        int total) {
  if (flags[0] != (int)(sizeof(FT) == 2)) return;
  int i = blockIdx.x * blockDim.x + threadIdx.x;
  int stride = gridDim.x * blockDim.x;
  for (int t = i; t < total; t += stride) {
    int seg = 0;
    while (seg < 16 && t >= fp.ofs[seg] + fp.len[seg]) ++seg;
    canon[t] = (float)((const FT*)fp.p[seg])[t - fp.ofs[seg]];
  }
}

template <typename IT>
__global__ void k_cvt_idx(const IT* __restrict__ ei, int* __restrict__ eic,
                          const int* __restrict__ flags) {
  if (flags[1] != (int)(sizeof(IT) == 8)) return;
  int i = blockIdx.x * blockDim.x + threadIdx.x;
  int stride = gridDim.x * blockDim.x;
  for (int t = i; t < 2 * NE; t += stride) eic[t] = (int)ei[t];
}

// ---------------- utility: zero fill ----------------
__global__ void k_zero4(f32x4* __restrict__ p, int n4) {
  int i = blockIdx.x * blockDim.x + threadIdx.x;
  int stride = gridDim.x * blockDim.x;
  f32x4 z = {0.f, 0.f, 0.f, 0.f};
  for (int t = i; t < n4; t += stride) p[t] = z;
}

// ---------------- CSR build: count, scan, fill ----------------
__global__ void k_count(const int* __restrict__ eic, int* __restrict__ cnt) {
  int i = blockIdx.x * blockDim.x + threadIdx.x;
  int stride = gridDim.x * blockDim.x;
  for (int e = i; e < NE; e += stride) atomicAdd(&cnt[eic[NE + e]], 1);
}

__global__ void k_dinv(const int* __restrict__ cnt, float* __restrict__ d) {
  int n = blockIdx.x * blockDim.x + threadIdx.x;
  if (n < NN) d[n] = rsqrtf((float)cnt[n] + 1.0f);  // self-loop
}

__global__ void k_scan1(const int* __restrict__ cnt, int* __restrict__ rowptr,
                        int* __restrict__ bsum, int nvals) {
  __shared__ int tmp[256];
  int gid = blockIdx.x * 256 + threadIdx.x;
  int v = (gid < nvals) ? cnt[gid] : 0;
  tmp[threadIdx.x] = v;
  __syncthreads();
  for (int s = 1; s < 256; s <<= 1) {
    int add = (threadIdx.x >= s) ? tmp[threadIdx.x - s] : 0;
    __syncthreads();
    tmp[threadIdx.x] += add;
    __syncthreads();
  }
  if (gid < nvals) rowptr[gid] = tmp[threadIdx.x] - v;  // exclusive within block
  if (threadIdx.x == 255) bsum[blockIdx.x] = tmp[255];
}

__global__ void k_scan2(int* __restrict__ bsum, int* __restrict__ btop, int nblocks) {
  __shared__ int tmp[512];
  int v = (threadIdx.x < nblocks) ? bsum[threadIdx.x] : 0;
  tmp[threadIdx.x] = v;
  __syncthreads();
  for (int s = 1; s < 512; s <<= 1) {
    int add = (threadIdx.x >= s) ? tmp[threadIdx.x - s] : 0;
    __syncthreads();
    tmp[threadIdx.x] += add;
    __syncthreads();
  }
  if (threadIdx.x < nblocks) btop[threadIdx.x] = tmp[threadIdx.x] - v;  // exclusive
}

__global__ void k_scan3(int* __restrict__ rowptr, const int* __restrict__ btop,
                        int* __restrict__ cursor, int nvals) {
  int gid = blockIdx.x * 256 + threadIdx.x;
  if (gid < nvals) {
    int v = rowptr[gid] + btop[blockIdx.x];
    rowptr[gid] = v;
    cursor[gid] = v;
  }
}

__global__ void k_fill(const int* __restrict__ eic, int* __restrict__ cursor,
                       int* __restrict__ csr_src) {
  int i = blockIdx.x * blockDim.x + threadIdx.x;
  int stride = gridDim.x * blockDim.x;
  for (int e = i; e < NE; e += stride) {
    int src = eic[e], dst = eic[NE + e];
    int pos = atomicAdd(&cursor[dst], 1);
    csr_src[pos] = src;
  }
}

// ---------------- layer 1: hs = (x @ W1) * dinv ----------------
__global__ void k_xw1(const float* __restrict__ x, const float* __restrict__ W1,
                      const float* __restrict__ dinv, float* __restrict__ hs) {
  int gid = blockIdx.x * blockDim.x + threadIdx.x;
  if (gid >= NN * HID) return;
  int n = gid >> 6, j = gid & 63;
  float acc = x[n * 3 + 0] * W1[0 * 64 + j] + x[n * 3 + 1] * W1[1 * 64 + j] +
              x[n * 3 + 2] * W1[2 * 64 + j];
  hs[gid] = acc * dinv[n];
}

// ---------------- hs = (h @ W) * dinv ----------------
__global__ __launch_bounds__(256) void k_hw(const float* __restrict__ h,
                                            const float* __restrict__ W,
                                            const float* __restrict__ dinv,
                                            float* __restrict__ hs) {
  __shared__ float Wl[64 * 64];
  __shared__ float hrow[4][64];
  int tid = threadIdx.x;
  for (int i = tid; i < 64 * 64; i += 256) Wl[i] = W[i];
  __syncthreads();
  int w = tid >> 6, j = tid & 63;
  for (int nb = blockIdx.x * 4 + w; nb < NN; nb += gridDim.x * 4) {
    hrow[w][j] = h[nb * 64 + j];
    LDS_FENCE();
    float acc = 0.f;
#pragma unroll 8
    for (int k = 0; k < 64; ++k) acc += hrow[w][k] * Wl[k * 64 + j];
    hs[nb * 64 + j] = acc * dinv[nb];
  }
}

// ---------------- gather-aggregate + fused finalize ----------------
// MODE 0: agg_out = relu(dinv*(sum + self) + b)     (float, next-layer input)
// MODE 1: h3p hi/lo split of dinv*(sum + self) + b  (bf16 pairs)
template <int MODE>
__global__ __launch_bounds__(256) void k_gather(const int* __restrict__ rowptr,
                                                const int* __restrict__ cnt,
                                                const int* __restrict__ csr_src,
                                                const float* __restrict__ hs,
                                                const float* __restrict__ dinv,
                                                const float* __restrict__ b,
                                                float* __restrict__ outf,
                                                bf16_t* __restrict__ h3p) {
  int wid = (blockIdx.x * blockDim.x + threadIdx.x) >> 6;
  int nw = (gridDim.x * blockDim.x) >> 6;
  int j = threadIdx.x & 63;
  for (int n = wid; n < NN; n += nw) {
    int beg = rowptr[n], c = cnt[n];
    float acc = hs[n * 64 + j];  // self-loop
    int k = 0;
    for (; k + 4 <= c; k += 4) {
      int s0 = csr_src[beg + k + 0], s1 = csr_src[beg + k + 1];
      int s2 = csr_src[beg + k + 2], s3 = csr_src[beg + k + 3];
      float v0 = hs[s0 * 64 + j], v1 = hs[s1 * 64 + j];
      float v2 = hs[s2 * 64 + j], v3 = hs[s3 * 64 + j];
      acc += (v0 + v1) + (v2 + v3);
    }
    for (; k < c; ++k) acc += hs[csr_src[beg + k] * 64 + j];
    float v = acc * dinv[n] + b[j];
    if (MODE == 0) {
      outf[n * 64 + j] = fmaxf(v, 0.f);
    } else {
      bf16_t hi = (bf16_t)v;
      h3p[n * 128 + j] = hi;
      h3p[n * 128 + 64 + j] = (bf16_t)(v - (float)hi);
    }
  }
}

// ---------------- shared MLP helpers (unchanged from passing round) ----------------
__device__ __forceinline__ void compute_a1(const int* __restrict__ eic,
                                           const bf16_t* __restrict__ h3p, int t, int n, int q,
                                           const bf16x8 b1h[4][4], const float bias1[4],
                                           f32x4 a1c[4]) {
  int e = t * 16 + n;
  int src = eic[e], dst = eic[NE + e];
  const bf16x8* ps = (const bf16x8*)(h3p + src * 128);
  const bf16x8* pd = (const bf16x8*)(h3p + dst * 128);
  bf16x8 a0h = ps[q], a1h = ps[4 + q], a0l = ps[8 + q], a1l = ps[12 + q];
  bf16x8 a2h = pd[q], a3h = pd[4 + q], a2l = pd[8 + q], a3l = pd[12 + q];
#pragma unroll
  for (int ct = 0; ct < 4; ++ct) {
    f32x4 c = {0.f, 0.f, 0.f, 0.f};
    c = __builtin_amdgcn_mfma_f32_16x16x32_bf16(a0h, b1h[0][ct], c, 0, 0, 0);
    c = __builtin_amdgcn_mfma_f32_16x16x32_bf16(a0l, b1h[0][ct], c, 0, 0, 0);
    c = __builtin_amdgcn_mfma_f32_16x16x32_bf16(a1h, b1h[1][ct], c, 0, 0, 0);
    c = __builtin_amdgcn_mfma_f32_16x16x32_bf16(a1l, b1h[1][ct], c, 0, 0, 0);
    c = __builtin_amdgcn_mfma_f32_16x16x32_bf16(a2h, b1h[2][ct], c, 0, 0, 0);
    c = __builtin_amdgcn_mfma_f32_16x16x32_bf16(a2l, b1h[2][ct], c, 0, 0, 0);
    c = __builtin_amdgcn_mfma_f32_16x16x32_bf16(a3h, b1h[3][ct], c, 0, 0, 0);
    c = __builtin_amdgcn_mfma_f32_16x16x32_bf16(a3l, b1h[3][ct], c, 0, 0, 0);
#pragma unroll
    for (int r = 0; r < 4; ++r) a1c[ct][r] = fmaxf(c[r] + bias1[ct], 0.f);
  }
}

__device__ __forceinline__ void load_b1(const float* __restrict__ Wm1f, int n, int q,
                                        bf16x8 b1h[4][4], const float* __restrict__ bm1f,
                                        float bias1[4]) {
#pragma unroll
  for (int ks = 0; ks < 4; ++ks)
#pragma unroll
    for (int ct = 0; ct < 4; ++ct)
#pragma unroll
      for (int j = 0; j < 8; ++j)
        b1h[ks][ct][j] = (bf16_t)Wm1f[(ks * 32 + q * 8 + j) * 64 + ct * 16 + n];
#pragma unroll
  for (int ct = 0; ct < 4; ++ct) bias1[ct] = bm1f[ct * 16 + n];
}

__device__ __forceinline__ void compute_a2(float zt[16][68], int wv_unused, int n, int q,
                                           const f32x4 a1c[4], const float s1c[4],
                                           const float t1c[4], const bf16x8 b2h[2][2],
                                           const float bias2[2], f32x4 a2c[2]) {
#pragma unroll
  for (int ct = 0; ct < 4; ++ct)
#pragma unroll
    for (int r = 0; r < 4; ++r)
      zt[q * 4 + r][ct * 16 + n] = a1c[ct][r] * s1c[ct] + t1c[ct];
  LDS_FENCE();
  bf16x8 g0h, g0l, g1h, g1l;
#pragma unroll
  for (int j = 0; j < 8; ++j) {
    float z0 = zt[n][q * 8 + j];
    float z1 = zt[n][32 + q * 8 + j];
    bf16_t h0 = (bf16_t)z0, h1 = (bf16_t)z1;
    g0h[j] = h0; g0l[j] = (bf16_t)(z0 - (float)h0);
    g1h[j] = h1; g1l[j] = (bf16_t)(z1 - (float)h1);
  }
#pragma unroll
  for (int ct = 0; ct < 2; ++ct) {
    f32x4 c = {0.f, 0.f, 0.f, 0.f};
    c = __builtin_amdgcn_mfma_f32_16x16x32_bf16(g0h, b2h[0][ct], c, 0, 0, 0);
    c = __builtin_amdgcn_mfma_f32_16x16x32_bf16(g0l, b2h[0][ct], c, 0, 0, 0);
    c = __builtin_amdgcn_mfma_f32_16x16x32_bf16(g1h, b2h[1][ct], c, 0, 0, 0);
    c = __builtin_amdgcn_mfma_f32_16x16x32_bf16(g1l, b2h[1][ct], c, 0, 0, 0);
#pragma unroll
    for (int r = 0; r < 4; ++r) a2c[ct][r] = fmaxf(c[r] + bias2[ct], 0.f);
  }
}

__device__ __forceinline__ void load_b2(const float* __restrict__ Wm2f, int n, int q,
                                        bf16x8 b2h[2][2], const float* __restrict__ bm2f,
                                        float bias2[2]) {
#pragma unroll
  for (int ks = 0; ks < 2; ++ks)
#pragma unroll
    for (int ct = 0; ct < 2; ++ct)
#pragma unroll
      for (int j = 0; j < 8; ++j)
        b2h[ks][ct][j] = (bf16_t)Wm2f[(ks * 32 + q * 8 + j) * 32 + ct * 16 + n];
#pragma unroll
  for (int ct = 0; ct < 2; ++ct) bias2[ct] = bm2f[ct * 16 + n];
}

// ============ pass 1: stats of a1 ============
__global__ __launch_bounds__(256) void k_stats1(const int* __restrict__ eic,
                                                const bf16_t* __restrict__ h3p,
                                                const float* __restrict__ Wm1f,
                                                const float* __restrict__ bm1f,
                                                float* __restrict__ sum1,
                                                float* __restrict__ sq1) {
  int lane = threadIdx.x & 63;
  int wave = blockIdx.x * 4 + (threadIdx.x >> 6);
  int nwaves = gridDim.x * 4;
  int n = lane & 15, q = lane >> 4;
  bf16x8 b1h[4][4];
  float bias1[4];
  load_b1(Wm1f, n, q, b1h, bm1f, bias1);
  float accs[4] = {0, 0, 0, 0}, accq[4] = {0, 0, 0, 0};
  for (int t = wave; t < NE / 16; t += nwaves) {
    f32x4 a1c[4];
    compute_a1(eic, h3p, t, n, q, b1h, bias1, a1c);
#pragma unroll
    for (int ct = 0; ct < 4; ++ct)
#pragma unroll
      for (int r = 0; r < 4; ++r) {
        accs[ct] += a1c[ct][r];
        accq[ct] += a1c[ct][r] * a1c[ct][r];
      }
  }
#pragma unroll
  for (int ct = 0; ct < 4; ++ct) {
    float s = accs[ct], qq = accq[ct];
    s += __shfl_xor(s, 16); s += __shfl_xor(s, 32);
    qq += __shfl_xor(qq, 16); qq += __shfl_xor(qq, 32);
    if (lane < 16) {
      unsafeAtomicAdd(&sum1[ct * 16 + lane], s);
      unsafeAtomicAdd(&sq1[ct * 16 + lane], qq);
    }
  }
}

// ---------------- BN affine constants ----------------
__global__ void k_bnconst(const float* __restrict__ sum, const float* __restrict__ sq,
                          const float* __restrict__ g, const float* __restrict__ be,
                          float* __restrict__ sarr, float* __restrict__ tarr, int ncol) {
  int j = threadIdx.x;
  if (j >= ncol) return;
  float mu = sum[j] / (float)NE;
  float var = fmaxf(sq[j] / (float)NE - mu * mu, 0.f);
  float s = g[j] * rsqrtf(var + EPS);
  sarr[j] = s;
  tarr[j] = be[j] - mu * s;
}

// ============ pass 2: stats of a2 ============
__global__ __launch_bounds__(256) void k_stats2(const int* __restrict__ eic,
                                                const bf16_t* __restrict__ h3p,
                                                const float* __restrict__ Wm1f,
                                                const float* __restrict__ bm1f,
                                                const float* __restrict__ s1, const float* __restrict__ t1,
                                                const float* __restrict__ Wm2f,
                                                const float* __restrict__ bm2f,
                                                float* __restrict__ sum2,
                                                float* __restrict__ sq2) {
  __shared__ float zt[4][16][68];
  int lane = threadIdx.x & 63;
  int wv = threadIdx.x >> 6;
  int wave = blockIdx.x * 4 + wv;
  int nwaves = gridDim.x * 4;
  int n = lane & 15, q = lane >> 4;
  bf16x8 b1h[4][4];
  float bias1[4];
  load_b1(Wm1f, n, q, b1h, bm1f, bias1);
  bf16x8 b2h[2][2];
  float bias2[2];
  load_b2(Wm2f, n, q, b2h, bm2f, bias2);
  float s1c[4], t1c[4];
#pragma unroll
  for (int ct = 0; ct < 4; ++ct) { s1c[ct] = s1[ct * 16 + n]; t1c[ct] = t1[ct * 16 + n]; }
  float accs[2] = {0, 0}, accq[2] = {0, 0};
  for (int t = wave; t < NE / 16; t += nwaves) {
    f32x4 a1c[4], a2c[2];
    compute_a1(eic, h3p, t, n, q, b1h, bias1, a1c);
    compute_a2(zt[wv], wv, n, q, a1c, s1c, t1c, b2h, bias2, a2c);
#pragma unroll
    for (int ct = 0; ct < 2; ++ct)
#pragma unroll
      for (int r = 0; r < 4; ++r) {
        accs[ct] += a2c[ct][r];
        accq[ct] += a2c[ct][r] * a2c[ct][r];
      }
  }
#pragma unroll
  for (int ct = 0; ct < 2; ++ct) {
    float s = accs[ct], qq = accq[ct];
    s += __shfl_xor(s, 16); s += __shfl_xor(s, 32);
    qq += __shfl_xor(qq, 16); qq += __shfl_xor(qq, 32);
    if (lane < 16) {
      unsafeAtomicAdd(&sum2[ct * 16 + lane], s);
      unsafeAtomicAdd(&sq2[ct * 16 + lane], qq);
    }
  }
}

// ============ pass 3: full recompute + BN2 + final dot -> out ============
template <typename OT>
__global__ __launch_bounds__(256) void k_out(const int* __restrict__ eic,
                                             const bf16_t* __restrict__ h3p,
                                             const float* __restrict__ Wm1f,
                                             const float* __restrict__ bm1f,
                                             const float* __restrict__ s1, const float* __restrict__ t1,
                                             const float* __restrict__ Wm2f,
                                             const float* __restrict__ bm2f,
                                             const float* __restrict__ s2, const float* __restrict__ t2,
                                             const float* __restrict__ Wm3f,
                                             const float* __restrict__ bm3f,
                                             OT* __restrict__ out,
                                             const int* __restrict__ flags) {
  if (flags[0] != (int)(sizeof(OT) == 2)) return;
  __shared__ float zt[4][16][68];
  int lane = threadIdx.x & 63;
  int wv = threadIdx.x >> 6;
  int wave = blockIdx.x * 4 + wv;
  int nwaves = gridDim.x * 4;
  int n = lane & 15, q = lane >> 4;
  bf16x8 b1h[4][4];
  float bias1[4];
  load_b1(Wm1f, n, q, b1h, bm1f, bias1);
  bf16x8 b2h[2][2];
  float bias2[2];
  load_b2(Wm2f, n, q, b2h, bm2f, bias2);
  float s1c[4], t1c[4];
#pragma unroll
  for (int ct = 0; ct < 4; ++ct) { s1c[ct] = s1[ct * 16 + n]; t1c[ct] = t1[ct * 16 + n]; }
  float s2c[2], t2c[2];
#pragma unroll
  for (int ct = 0; ct < 2; ++ct) { s2c[ct] = s2[ct * 16 + n]; t2c[ct] = t2[ct * 16 + n]; }
  float w3a0 = Wm3f[n * 2 + 0], w3a1 = Wm3f[n * 2 + 1];
  float w3b0 = Wm3f[(16 + n) * 2 + 0], w3b1 = Wm3f[(16 + n) * 2 + 1];
  float bb0 = bm3f[0], bb1 = bm3f[1];

  for (int t = wave; t < NE / 16; t += nwaves) {
    f32x4 a1c[4], a2c[2];
    compute_a1(eic, h3p, t, n, q, b1h, bias1, a1c);
    compute_a2(zt[wv], wv, n, q, a1c, s1c, t1c, b2h, bias2, a2c);
#pragma unroll
    for (int r = 0; r < 4; ++r) {
      float z0 = a2c[0][r] * s2c[0] + t2c[0];
      float z1 = a2c[1][r] * s2c[1] + t2c[1];
      float o0 = z0 * w3a0 + z1 * w3b0;
      float o1 = z0 * w3a1 + z1 * w3b1;
      o0 += __shfl_xor(o0, 1); o0 += __shfl_xor(o0, 2);
      o0 += __shfl_xor(o0, 4); o0 += __shfl_xor(o0, 8);
      o1 += __shfl_xor(o1, 1); o1 += __shfl_xor(o1, 2);
      o1 += __shfl_xor(o1, 4); o1 += __shfl_xor(o1, 8);
      if (n == 0) {
        int eo = t * 16 + q * 4 + r;
        out[eo * 2 + 0] = (OT)(o0 + bb0);
        out[eo * 2 + 1] = (OT)(o1 + bb1);
      }
    }
  }
}

// ---------------- host ----------------
extern "C" void kernel_launch(void* const* d_in, const int* in_sizes, int n_in,
                              void* d_out, int out_size, void* d_ws, size_t ws_size,
                              hipStream_t stream) {
  (void)n_in; (void)in_sizes; (void)out_size; (void)ws_size;

  char* ws = (char*)d_ws;
  size_t off = 0;
  auto alloc = [&](size_t bytes) {
    size_t r = off;
    off = (off + bytes + 255) & ~(size_t)255;
    return r;
  };
  float* dinv  = (float*)(ws + alloc((size_t)NN * 4));
  float* hs    = (float*)(ws + alloc((size_t)NN * HID * 4));
  float* agg   = (float*)(ws + alloc((size_t)NN * HID * 4));
  bf16_t* h3p  = (bf16_t*)(ws + alloc((size_t)NN * 128 * 2));  // hi/lo rows of 128
  int*   eic   = (int*)(ws + alloc((size_t)2 * NE * 4));
  float* stats = (float*)(ws + alloc(192 * 4));
  float* sum1 = stats, *sq1 = stats + 64, *sum2 = stats + 128, *sq2 = stats + 160;
  int*   flags = (int*)(ws + alloc(256));
  float* s1arr = (float*)(ws + alloc(64 * 4));
  float* t1arr = (float*)(ws + alloc(64 * 4));
  float* s2arr = (float*)(ws + alloc(32 * 4));
  float* t2arr = (float*)(ws + alloc(32 * 4));
  // CSR
  int* cnt     = (int*)(ws + alloc((size_t)NN * 4));
  int* rowptr  = (int*)(ws + alloc((size_t)NN * 4));
  int* cursor  = (int*)(ws + alloc((size_t)NN * 4));
  int* bsum    = (int*)(ws + alloc(512 * 4));
  int* btop    = (int*)(ws + alloc(512 * 4));
  int* csr_src = (int*)(ws + alloc((size_t)NE * 4));

  // canonical f32 input block
  static const int flens[17] = {NN * 3, 3 * 64, 64, 64 * 64, 64, 64 * 64, 64,
                                128 * 64, 64, 64, 64, 64 * 32, 32, 32, 32, 32 * 2, 2};
  FPtrs fp;
  int total_f = 0;
  {
    int fi = 0;
    for (int i = 0; i < 18; ++i) {
      if (i == 1) continue;
      fp.p[fi] = d_in[i];
      fp.len[fi] = flens[fi];
      fp.ofs[fi] = total_f;
      total_f += flens[fi];
      ++fi;
    }
  }
  float* canon = (float*)(ws + alloc((size_t)total_f * 4));

  const float* xf   = canon + fp.ofs[0];
  const float* W1f  = canon + fp.ofs[1];
  const float* b1f  = canon + fp.ofs[2];
  const float* W2f  = canon + fp.ofs[3];
  const float* b2f  = canon + fp.ofs[4];
  const float* W3f  = canon + fp.ofs[5];
  const float* b3f  = canon + fp.ofs[6];
  const float* Wm1f = canon + fp.ofs[7];
  const float* bm1f = canon + fp.ofs[8];
  const float* g1f  = canon + fp.ofs[9];
  const float* be1f = canon + fp.ofs[10];
  const float* Wm2f = canon + fp.ofs[11];
  const float* bm2f = canon + fp.ofs[12];
  const float* g2f  = canon + fp.ofs[13];
  const float* be2f = canon + fp.ofs[14];
  const float* Wm3f = canon + fp.ofs[15];
  const float* bm3f = canon + fp.ofs[16];

  const int nh = NN * HID;
  const int nscanb = (NN + 255) / 256;  // 391

  // 0) detect dtypes, canonicalize
  k_detect<<<1, 64, 0, stream>>>((const unsigned*)d_in[0], (const int*)d_in[1], flags);
  k_cvt_idx<int><<<1600, 256, 0, stream>>>((const int*)d_in[1], eic, flags);
  k_cvt_idx<long long><<<1600, 256, 0, stream>>>((const long long*)d_in[1], eic, flags);
  k_cvt_f<float><<<640, 256, 0, stream>>>(fp, canon, flags, total_f);
  k_cvt_f<bf16_t><<<640, 256, 0, stream>>>(fp, canon, flags, total_f);

  // 1) CSR build (once, reused by all 3 layers) + dinv + stats zero
  k_zero4<<<128, 256, 0, stream>>>((f32x4*)cnt, NN / 4);
  k_zero4<<<1, 64, 0, stream>>>((f32x4*)stats, 48);
  k_count<<<1600, 256, 0, stream>>>(eic, cnt);
  k_dinv<<<(NN + 255) / 256, 256, 0, stream>>>(cnt, dinv);
  k_scan1<<<nscanb, 256, 0, stream>>>(cnt, rowptr, bsum, NN);
  k_scan2<<<1, 512, 0, stream>>>(bsum, btop, nscanb);
  k_scan3<<<nscanb, 256, 0, stream>>>(rowptr, btop, cursor, NN);
  k_fill<<<1600, 256, 0, stream>>>(eic, cursor, csr_src);

  // ---- GCN layer 1 ----
  k_xw1<<<(nh + 255) / 256, 256, 0, stream>>>(xf, W1f, dinv, hs);
  k_gather<0><<<2048, 256, 0, stream>>>(rowptr, cnt, csr_src, hs, dinv, b1f, agg, nullptr);

  // ---- GCN layer 2 ----
  k_hw<<<4096, 256, 0, stream>>>(agg, W2f, dinv, hs);
  k_gather<0><<<2048, 256, 0, stream>>>(rowptr, cnt, csr_src, hs, dinv, b2f, agg, nullptr);

  // ---- GCN layer 3 (bf16 hi/lo split out) ----
  k_hw<<<4096, 256, 0, stream>>>(agg, W3f, dinv, hs);
  k_gather<1><<<2048, 256, 0, stream>>>(rowptr, cnt, csr_src, hs, dinv, b3f, nullptr, h3p);

  // ---- edge MLP (3-pass, BN applied in-register post-stats) ----
  k_stats1<<<2048, 256, 0, stream>>>(eic, h3p, Wm1f, bm1f, sum1, sq1);
  k_bnconst<<<1, 64, 0, stream>>>(sum1, sq1, g1f, be1f, s1arr, t1arr, 64);
  k_stats2<<<2048, 256, 0, stream>>>(eic, h3p, Wm1f, bm1f, s1arr, t1arr, Wm2f, bm2f, sum2, sq2);
  k_bnconst<<<1, 64, 0, stream>>>(sum2, sq2, g2f, be2f, s2arr, t2arr, 32);
  k_out<float><<<2048, 256, 0, stream>>>(eic, h3p, Wm1f, bm1f, s1arr, t1arr, Wm2f, bm2f,
                                         s2arr, t2arr, Wm3f, bm3f, (float*)d_out, flags);
  k_out<bf16_t><<<2048, 256, 0, stream>>>(eic, h3p, Wm1f, bm1f, s1arr, t1arr, Wm2f, bm2f,
                                          s2arr, t2arr, Wm3f, bm3f, (bf16_t*)d_out, flags);
}